// Round 18
// baseline (78.599 us; speedup 1.0000x reference)
//
#include <hip/hip_runtime.h>
#include <hip/hip_bf16.h>
#include <cstddef>

// ---------------------------------------------------------------------------
// MORP: Lu = irfft( g(k) * rfft( h(u) ) ), h/g tiny MLPs (1->64->64->{1,2}, ELU)
// B=2048 rows, N=8192, M=4097, W=64.
// Round 18 = Round 17 with the cvt_pkrtz TYPE FIX (h2 must be __fp16x2, the
// builtin's actual return type, not _Float16x2). Plan unchanged:
//  - fp16x2-packed LDS: 32KB/block -> 4 blocks/CU = 8 waves/SIMD (was 2/4).
//    fp16 rounding at Z-scale contributes ~5e-4 to output (floor 0.375);
//    range safe (|Z|max ~few thousand << 65504).
//  - pack v_cvt_pkrtz (1 instr), unpack 2 cvt; LDS ops b64->b32.
//  - swizzle b32-tuned: swz(i)=i^((i>>3)&7)^(((i>>6)&7)<<2) (S1 const 68);
//    invS2->S3g handoff adds ^digit3. All stages 2 lanes/bank.
// Out-of-place only (in-place BANNED); register arrays fully unrolled.
// ---------------------------------------------------------------------------

#define TWO_PI_F 6.28318530717958647693f

struct __align__(8) cpx { float x, y; };
typedef __fp16 h2 __attribute__((ext_vector_type(2)));

__device__ __forceinline__ h2 cpk(cpx a) {
    return __builtin_amdgcn_cvt_pkrtz(a.x, a.y);
}
__device__ __forceinline__ cpx cup(h2 p) {
    return cpx{(float)p.x, (float)p.y};
}

__device__ __forceinline__ cpx cmul(cpx a, cpx b) {
    return cpx{fmaf(a.x, b.x, -a.y * b.y), fmaf(a.x, b.y, a.y * b.x)};
}
__device__ __forceinline__ cpx cadd(cpx a, cpx b) { return cpx{a.x + b.x, a.y + b.y}; }
__device__ __forceinline__ cpx csub(cpx a, cpx b) { return cpx{a.x - b.x, a.y - b.y}; }
__device__ __forceinline__ cpx cscale(float s, cpx a) { return cpx{s * a.x, s * a.y}; }
__device__ __forceinline__ cpx cconj(cpx a) { return cpx{a.x, -a.y}; }
template <int S>
__device__ __forceinline__ cpx crot(cpx z) {   // multiply by S<0 ? -i : +i
    return (S < 0) ? cpx{z.y, -z.x} : cpx{-z.y, z.x};
}

__device__ __forceinline__ float elu(float x) {
    return x > 0.0f ? x : (__expf(x) - 1.0f);
}

// LDS index swizzle, b32-bank-tuned (bits 0-8 only; bits >=9 untouched).
__device__ __forceinline__ int swz(int i) {
    return i ^ ((i >> 3) & 7) ^ (((i >> 6) & 7) << 2);
}

// ---------------------------------------------------------------------------
// In-register 4/8-point DFT (natural order), sign S (-1 fwd, +1 inv).
// ---------------------------------------------------------------------------
template <int S>
__device__ __forceinline__ void dft4(cpx& x0, cpx& x1, cpx& x2, cpx& x3) {
    cpx e0 = cadd(x0, x2), e1 = csub(x0, x2);
    cpx o0 = cadd(x1, x3), o1 = crot<S>(csub(x1, x3));
    x0 = cadd(e0, o0);
    x1 = cadd(e1, o1);
    x2 = csub(e0, o0);
    x3 = csub(e1, o1);
}

template <int S>
__device__ __forceinline__ void dft8(cpx v[8]) {
    constexpr float r = 0.70710678118654752f;
    cpx E0 = v[0], E1 = v[2], E2 = v[4], E3 = v[6];
    cpx O0 = v[1], O1 = v[3], O2 = v[5], O3 = v[7];
    dft4<S>(E0, E1, E2, E3);
    dft4<S>(O0, O1, O2, O3);
    O1 = (S < 0) ? cpx{r * (O1.x + O1.y), r * (O1.y - O1.x)}
                 : cpx{r * (O1.x - O1.y), r * (O1.x + O1.y)};
    O2 = crot<S>(O2);
    O3 = (S < 0) ? cpx{r * (O3.y - O3.x), -r * (O3.x + O3.y)}
                 : cpx{-r * (O3.x + O3.y), r * (O3.x - O3.y)};
    v[0] = cadd(E0, O0);
    v[1] = cadd(E1, O1);
    v[2] = cadd(E2, O2);
    v[3] = cadd(E3, O3);
    v[4] = csub(E0, O0);
    v[5] = csub(E1, O1);
    v[6] = csub(E2, O2);
    v[7] = csub(E3, O3);
}

// Apply w^t, t=1..7, with w = cis(ang); depth-3 product tree.
template <int S>
__device__ __forceinline__ void twiddle8(cpx v[8], float ang) {
    cpx w;
    __sincosf(ang, &w.y, &w.x);
    const cpx t2 = cmul(w, w);
    const cpx t3 = cmul(t2, w);
    const cpx t4 = cmul(t2, t2);
    const cpx t5 = cmul(t4, w);
    const cpx t6 = cmul(t4, t2);
    const cpx t7 = cmul(t4, t3);
    v[1] = cmul(v[1], w);
    v[2] = cmul(v[2], t2);
    v[3] = cmul(v[3], t3);
    v[4] = cmul(v[4], t4);
    v[5] = cmul(v[5], t5);
    v[6] = cmul(v[6], t6);
    v[7] = cmul(v[7], t7);
}

// ---------------------------------------------------------------------------
// Radix-8 stages on fp16x2 LDS with precomputed swizzled bases.
// ---------------------------------------------------------------------------
template <int S>
__device__ __forceinline__ void stage1(const h2* __restrict__ src,
                                       h2* __restrict__ dst, int s1, int k4) {
    cpx v[8];
#pragma unroll
    for (int t = 0; t < 8; ++t) v[t] = cup(src[s1 ^ (68 * t)]);
    twiddle8<S>(v, (float)S * (TWO_PI_F / 64.0f) * (float)k4);
    dft8<S>(v);
#pragma unroll
    for (int t = 0; t < 8; ++t) dst[s1 ^ (68 * t)] = cpk(v[t]);
}

template <int S>
__device__ __forceinline__ void stage2(const h2* __restrict__ src,
                                       h2* __restrict__ dst, int s2r, int s2w,
                                       int m2) {
    cpx v[8];
#pragma unroll
    for (int t = 0; t < 8; ++t) v[t] = cup(src[s2r ^ (9 * t)]);
    twiddle8<S>(v, (float)S * (TWO_PI_F / 512.0f) * (float)m2);
    dft8<S>(v);
#pragma unroll
    for (int t = 0; t < 8; ++t) dst[s2w ^ (9 * t)] = cpk(v[t]);
}

template <int S>
__device__ __forceinline__ void stage3(const h2* __restrict__ src,
                                       h2* __restrict__ dst, int s3r, int s3w,
                                       int m3) {
    cpx v[8];
#pragma unroll
    for (int t = 0; t < 8; ++t) v[t] = cup(src[s3r ^ t]);
    twiddle8<S>(v, (float)S * (TWO_PI_F / 4096.0f) * (float)m3);
    dft8<S>(v);
    h2* __restrict__ pw = dst + s3w;
#pragma unroll
    for (int t = 0; t < 8; ++t) pw[512 * t] = cpk(v[t]);
}

// ---------------------------------------------------------------------------
// Kernel 1: blocks 0..16 -> gk[k]; blocks 17..33 -> htab (exact fp32 h).
// ---------------------------------------------------------------------------
__global__ __launch_bounds__(256, 2) void tables_kernel(
    const float* __restrict__ kin,
    const float* __restrict__ gw1, const float* __restrict__ gb1,
    const float* __restrict__ gw2, const float* __restrict__ gb2,
    const float* __restrict__ gw3, const float* __restrict__ gb3,
    const float* __restrict__ hw1, const float* __restrict__ hb1,
    const float* __restrict__ hw2, const float* __restrict__ hb2,
    const float* __restrict__ hw3, const float* __restrict__ hb3,
    cpx* __restrict__ gk_out, float* __restrict__ htab) {
    __shared__ __align__(16) float w2[4096];
    __shared__ float w1[64], b1[64], b2[64], w3a[64], w3b[64];
    __shared__ float b3a, b3b;
    const int tid = threadIdx.x;
    const bool isg = blockIdx.x < 17;
    const float* W1 = isg ? gw1 : hw1;
    const float* B1 = isg ? gb1 : hb1;
    const float* W2 = isg ? gw2 : hw2;
    const float* B2 = isg ? gb2 : hb2;
    for (int i = tid; i < 4096; i += 256) w2[i] = W2[i];
    if (tid < 64) {
        w1[tid] = W1[tid];
        b1[tid] = B1[tid];
        b2[tid] = B2[tid];
        if (isg) {
            w3a[tid] = gw3[tid * 2 + 0];
            w3b[tid] = gw3[tid * 2 + 1];
        } else {
            w3a[tid] = hw3[tid];
            w3b[tid] = 0.0f;
        }
    }
    if (tid == 0) {
        b3a = isg ? gb3[0] : hb3[0];
        b3b = isg ? gb3[1] : 0.0f;
    }
    __syncthreads();
    const int idx = (isg ? blockIdx.x : blockIdx.x - 17) * 256 + tid;
    if (idx >= 4097) return;
    const float x = isg ? kin[idx] : (-8.0f + (float)idx * (16.0f / 4096.0f));
    float acc[64];
#pragma unroll
    for (int i = 0; i < 64; ++i) acc[i] = b2[i];
#pragma unroll 2
    for (int j = 0; j < 64; ++j) {
        float h1 = elu(fmaf(x, w1[j], b1[j]));
        const float4* wr = (const float4*)&w2[j * 64];
#pragma unroll
        for (int q = 0; q < 16; ++q) {
            float4 wv = wr[q];
            acc[q * 4 + 0] = fmaf(h1, wv.x, acc[q * 4 + 0]);
            acc[q * 4 + 1] = fmaf(h1, wv.y, acc[q * 4 + 1]);
            acc[q * 4 + 2] = fmaf(h1, wv.z, acc[q * 4 + 2]);
            acc[q * 4 + 3] = fmaf(h1, wv.w, acc[q * 4 + 3]);
        }
    }
    float oa = b3a, ob = b3b;
#pragma unroll
    for (int i = 0; i < 64; ++i) {
        float h2v = elu(acc[i]);
        oa = fmaf(h2v, w3a[i], oa);
        ob = fmaf(h2v, w3b[i], ob);
    }
    if (isg) gk_out[idx] = cpx{oa, ob};
    else htab[idx] = oa;
}

// ---------------------------------------------------------------------------
// Kernel 1b: ab[k] — basis evaluation of the bilinear spectral map.
// Zi[k] = A*Zk + B*conj(Z[4096-k]), invn folded in.
// ---------------------------------------------------------------------------
__device__ __forceinline__ cpx spectral_eval(cpx Zk, cpx Zc, cpx w,
                                             cpx gkk, cpx gkm) {
    const cpx s = cadd(Zk, Zc);
    const cpx d = csub(Zk, Zc);
    const cpx wd = cmul(w, d);
    const cpx huh{0.5f * (s.x + wd.y), 0.5f * (s.y - wd.x)};
    const cpx Zr = cconj(Zc);
    const cpx Zkc = cconj(Zk);
    const cpx s2v = cadd(Zr, Zkc);
    const cpx d2v = csub(Zr, Zkc);
    const cpx wr{-w.x, w.y};
    const cpx wd2 = cmul(wr, d2v);
    const cpx huhr{0.5f * (s2v.x + wd2.y), 0.5f * (s2v.y - wd2.x)};
    const cpx Yk = cmul(gkk, huh);
    const cpx Yrc = cconj(cmul(gkm, huhr));
    const cpx E = cscale(0.5f, cadd(Yk, Yrc));
    const cpx D = cscale(0.5f, csub(Yk, Yrc));
    const cpx O = cmul(cconj(w), D);
    return cpx{E.x - O.y, E.y + O.x};
}

__global__ __launch_bounds__(256, 2) void ab_kernel(
    const cpx* __restrict__ gk, float4* __restrict__ ab) {
    const int k = blockIdx.x * 256 + threadIdx.x;   // 0..4095
    const float invn = 1.0f / 4096.0f;
    cpx w;
    {
        float ang = -TWO_PI_F * (float)k / 8192.0f;
        __sincosf(ang, &w.y, &w.x);
    }
    const cpx gkk = gk[k];
    const cpx gkm = gk[4096 - k];
    const cpx A = spectral_eval(cpx{1.0f, 0.0f}, cpx{0.0f, 0.0f}, w, gkk, gkm);
    const cpx B = spectral_eval(cpx{0.0f, 0.0f}, cpx{1.0f, 0.0f}, w, gkk, gkm);
    ab[k] = float4{A.x * invn, A.y * invn, B.x * invn, B.y * invn};
}

// ---------------------------------------------------------------------------
// Kernel 2: one 512-thread block per row, fp16x2 LDS (32KB -> 4 blocks/CU).
// fusedS0->A, S1 A->B, S2 B->A, S3 A->B, spectral+invS0 B->A,
// S1 A->B, S2 B->A(swz3), S3g A->GLOBAL coalesced (relabeled).
// ---------------------------------------------------------------------------
__global__ __launch_bounds__(512, 8) void morp_main(
    const float* __restrict__ u, const float* __restrict__ htab,
    const float4* __restrict__ ab, float* __restrict__ out) {
    __shared__ __align__(16) h2 bufA[4096];
    __shared__ __align__(16) h2 bufB[4096];
    const int tid = threadIdx.x;
    const int row = blockIdx.x;

    // ---- precomputed swizzled bases (once per thread)
    const int w3c = (tid >> 6) & 7;                           // wave id
    const int s0 = swz(tid);                                  // +512t
    const int b1 = (tid & 63) + 512 * (tid >> 6);
    const int s1 = b1 ^ ((b1 >> 3) & 7);                      // ^68t
    const int b2 = (tid & 7) + 64 * (tid >> 3);
    const int s2 = b2 ^ (((tid >> 3) & 7) << 2);              // ^9t
    const int b3 = 8 * (tid & 7) + 64 * (tid >> 3);
    const int s3r = b3 ^ (tid & 7) ^ (((tid >> 3) & 7) << 2); // ^t
    const int m3 = (tid >> 6) + 8 * ((tid >> 3) & 7) + 64 * (tid & 7);
    const int s3w = swz(m3);                                  // +512t
    // relabeled inverse-S3: thread tid runs butterfly q = m3 (involution);
    // reads the swz3 layout (swz ^ digit3), twiddle index m3(q)=tid.
    const int bq = 8 * (m3 & 7) + 64 * (m3 >> 3);
    const int s3g = bq ^ (m3 & 7) ^ (((m3 >> 3) & 7) << 2) ^ ((m3 >> 6) & 7);
    const int sm = swz(4096 - tid);                           // mirror: -512c
    const int k4 = tid >> 6;
    const int m2 = (tid >> 6) + 8 * ((tid >> 3) & 7);

    // ---- fused table-lerp + forward stage 0 (DFT8 over t4) -> bufA
    {
        const float2* urow2 = (const float2*)(u + (size_t)row * 8192);
        cpx v[8];
#pragma unroll
        for (int t = 0; t < 8; ++t) {
            const float2 uv = urow2[tid + 512 * t];
            float t0 = fmaf(uv.x, 256.0f, 2048.0f);
            t0 = fminf(fmaxf(t0, 0.0f), 4095.0f);
            const float fi0 = floorf(t0);
            const int i0 = (int)fi0;
            const float h00 = htab[i0], h01 = htab[i0 + 1];
            float t1 = fmaf(uv.y, 256.0f, 2048.0f);
            t1 = fminf(fmaxf(t1, 0.0f), 4095.0f);
            const float fi1 = floorf(t1);
            const int i1 = (int)fi1;
            const float h10 = htab[i1], h11 = htab[i1 + 1];
            v[t] = cpx{fmaf(t0 - fi0, h01 - h00, h00),
                       fmaf(t1 - fi1, h11 - h10, h10)};
        }
        dft8<-1>(v);
        h2* __restrict__ p = bufA + s0;
#pragma unroll
        for (int t = 0; t < 8; ++t) p[512 * t] = cpk(v[t]);
    }
    __syncthreads();
    stage1<-1>(bufA, bufB, s1, k4);
    __syncthreads();
    stage2<-1>(bufB, bufA, s2, s2, m2);
    __syncthreads();
    stage3<-1>(bufA, bufB, s3r, s3w, m3);
    __syncthreads();

    // ---- fused spectral (bilinear A/B) + inverse stage 0: B -> A
    {
        cpx zres[8];
        const h2* __restrict__ pk = bufB + s0;
        const int c0mir = (tid == 0) ? 0 : sm;
#pragma unroll
        for (int c = 0; c < 8; ++c) {
            const int k = tid + 512 * c;
            const float4 abv = ab[k];
            const cpx Zk = cup(pk[512 * c]);
            const cpx Zc = cconj(cup(bufB[c == 0 ? c0mir : (sm - 512 * c)]));
            const cpx az = cmul(cpx{abv.x, abv.y}, Zk);
            const cpx bz = cmul(cpx{abv.z, abv.w}, Zc);
            zres[c] = cadd(az, bz);
        }
        dft8<1>(zres);
        h2* __restrict__ pw = bufA + s0;
#pragma unroll
        for (int c = 0; c < 8; ++c) pw[512 * c] = cpk(zres[c]);
    }
    __syncthreads();
    stage1<1>(bufA, bufB, s1, k4);
    __syncthreads();
    stage2<1>(bufB, bufA, s2, s2 ^ w3c, m2);   // write generation in swz3
    __syncthreads();

    // ---- inverse S3, relabeled q = m3: read bufA (swz3), twiddle index tid,
    // write GLOBAL coalesced at n = tid + 512t. No copy-out.
    {
        cpx v[8];
#pragma unroll
        for (int t = 0; t < 8; ++t) v[t] = cup(bufA[s3g ^ t]);
        twiddle8<1>(v, (TWO_PI_F / 4096.0f) * (float)tid);
        dft8<1>(v);
        cpx* orow = (cpx*)(out + (size_t)row * 8192);
#pragma unroll
        for (int t = 0; t < 8; ++t) orow[tid + 512 * t] = v[t];
    }
}

extern "C" void kernel_launch(void* const* d_in, const int* in_sizes, int n_in,
                              void* d_out, int out_size, void* d_ws, size_t ws_size,
                              hipStream_t stream) {
    const float* u   = (const float*)d_in[0];
    const float* kin = (const float*)d_in[1];
    const float* hw1 = (const float*)d_in[2];
    const float* hb1 = (const float*)d_in[3];
    const float* hw2 = (const float*)d_in[4];
    const float* hb2 = (const float*)d_in[5];
    const float* hw3 = (const float*)d_in[6];
    const float* hb3 = (const float*)d_in[7];
    const float* gw1 = (const float*)d_in[8];
    const float* gb1 = (const float*)d_in[9];
    const float* gw2 = (const float*)d_in[10];
    const float* gb2 = (const float*)d_in[11];
    const float* gw3 = (const float*)d_in[12];
    const float* gb3 = (const float*)d_in[13];

    cpx* gk = (cpx*)d_ws;                               // 4097*8 = 32776 B
    float* htab = (float*)((char*)d_ws + 32832);        // 4097*4 = 16388 B
    float4* ab = (float4*)((char*)d_ws + 49280);        // 4096*16 = 65536 B
    tables_kernel<<<34, 256, 0, stream>>>(kin, gw1, gb1, gw2, gb2, gw3, gb3,
                                          hw1, hb1, hw2, hb2, hw3, hb3,
                                          gk, htab);
    ab_kernel<<<16, 256, 0, stream>>>(gk, ab);
    morp_main<<<2048, 512, 0, stream>>>(u, htab, ab, (float*)d_out);
}

// Round 19
// 74.390 us; speedup vs baseline: 1.0566x; 1.0566x over previous
//
#include <hip/hip_runtime.h>
#include <hip/hip_bf16.h>
#include <cstddef>

// ---------------------------------------------------------------------------
// MORP: Lu = irfft( g(k) * rfft( h(u) ) ), h/g tiny MLPs (1->64->64->{1,2}, ELU)
// B=2048 rows, N=8192, M=4097, W=64.
// Round 19 = Round 18 with ONE fix: __launch_bounds__(512,8) -> (512,4).
// r18's (512,8) capped VGPR at 32 (<52 needed) -> scratch spills (WRITE
// 65->94MB, FETCH 33->47MB), eating the occupancy win (dur 60us). With cap
// 128 the compiler uses its natural ~52 regs; actual usage <=64 still lets
// HW schedule 8 waves/SIMD = 4 blocks/CU (LDS 2x16KB allows 5).
// Everything else identical to r18 (fp16x2 LDS, b32-tuned swizzle, bilinear
// spectral, relabeled coalesced inv-S3). In-place FFT remains BANNED.
// ---------------------------------------------------------------------------

#define TWO_PI_F 6.28318530717958647693f

struct __align__(8) cpx { float x, y; };
typedef __fp16 h2 __attribute__((ext_vector_type(2)));

__device__ __forceinline__ h2 cpk(cpx a) {
    return __builtin_amdgcn_cvt_pkrtz(a.x, a.y);
}
__device__ __forceinline__ cpx cup(h2 p) {
    return cpx{(float)p.x, (float)p.y};
}

__device__ __forceinline__ cpx cmul(cpx a, cpx b) {
    return cpx{fmaf(a.x, b.x, -a.y * b.y), fmaf(a.x, b.y, a.y * b.x)};
}
__device__ __forceinline__ cpx cadd(cpx a, cpx b) { return cpx{a.x + b.x, a.y + b.y}; }
__device__ __forceinline__ cpx csub(cpx a, cpx b) { return cpx{a.x - b.x, a.y - b.y}; }
__device__ __forceinline__ cpx cscale(float s, cpx a) { return cpx{s * a.x, s * a.y}; }
__device__ __forceinline__ cpx cconj(cpx a) { return cpx{a.x, -a.y}; }
template <int S>
__device__ __forceinline__ cpx crot(cpx z) {   // multiply by S<0 ? -i : +i
    return (S < 0) ? cpx{z.y, -z.x} : cpx{-z.y, z.x};
}

__device__ __forceinline__ float elu(float x) {
    return x > 0.0f ? x : (__expf(x) - 1.0f);
}

// LDS index swizzle, b32-bank-tuned (bits 0-8 only; bits >=9 untouched).
__device__ __forceinline__ int swz(int i) {
    return i ^ ((i >> 3) & 7) ^ (((i >> 6) & 7) << 2);
}

// ---------------------------------------------------------------------------
// In-register 4/8-point DFT (natural order), sign S (-1 fwd, +1 inv).
// ---------------------------------------------------------------------------
template <int S>
__device__ __forceinline__ void dft4(cpx& x0, cpx& x1, cpx& x2, cpx& x3) {
    cpx e0 = cadd(x0, x2), e1 = csub(x0, x2);
    cpx o0 = cadd(x1, x3), o1 = crot<S>(csub(x1, x3));
    x0 = cadd(e0, o0);
    x1 = cadd(e1, o1);
    x2 = csub(e0, o0);
    x3 = csub(e1, o1);
}

template <int S>
__device__ __forceinline__ void dft8(cpx v[8]) {
    constexpr float r = 0.70710678118654752f;
    cpx E0 = v[0], E1 = v[2], E2 = v[4], E3 = v[6];
    cpx O0 = v[1], O1 = v[3], O2 = v[5], O3 = v[7];
    dft4<S>(E0, E1, E2, E3);
    dft4<S>(O0, O1, O2, O3);
    O1 = (S < 0) ? cpx{r * (O1.x + O1.y), r * (O1.y - O1.x)}
                 : cpx{r * (O1.x - O1.y), r * (O1.x + O1.y)};
    O2 = crot<S>(O2);
    O3 = (S < 0) ? cpx{r * (O3.y - O3.x), -r * (O3.x + O3.y)}
                 : cpx{-r * (O3.x + O3.y), r * (O3.x - O3.y)};
    v[0] = cadd(E0, O0);
    v[1] = cadd(E1, O1);
    v[2] = cadd(E2, O2);
    v[3] = cadd(E3, O3);
    v[4] = csub(E0, O0);
    v[5] = csub(E1, O1);
    v[6] = csub(E2, O2);
    v[7] = csub(E3, O3);
}

// Apply w^t, t=1..7, with w = cis(ang); depth-3 product tree.
template <int S>
__device__ __forceinline__ void twiddle8(cpx v[8], float ang) {
    cpx w;
    __sincosf(ang, &w.y, &w.x);
    const cpx t2 = cmul(w, w);
    const cpx t3 = cmul(t2, w);
    const cpx t4 = cmul(t2, t2);
    const cpx t5 = cmul(t4, w);
    const cpx t6 = cmul(t4, t2);
    const cpx t7 = cmul(t4, t3);
    v[1] = cmul(v[1], w);
    v[2] = cmul(v[2], t2);
    v[3] = cmul(v[3], t3);
    v[4] = cmul(v[4], t4);
    v[5] = cmul(v[5], t5);
    v[6] = cmul(v[6], t6);
    v[7] = cmul(v[7], t7);
}

// ---------------------------------------------------------------------------
// Radix-8 stages on fp16x2 LDS with precomputed swizzled bases.
// ---------------------------------------------------------------------------
template <int S>
__device__ __forceinline__ void stage1(const h2* __restrict__ src,
                                       h2* __restrict__ dst, int s1, int k4) {
    cpx v[8];
#pragma unroll
    for (int t = 0; t < 8; ++t) v[t] = cup(src[s1 ^ (68 * t)]);
    twiddle8<S>(v, (float)S * (TWO_PI_F / 64.0f) * (float)k4);
    dft8<S>(v);
#pragma unroll
    for (int t = 0; t < 8; ++t) dst[s1 ^ (68 * t)] = cpk(v[t]);
}

template <int S>
__device__ __forceinline__ void stage2(const h2* __restrict__ src,
                                       h2* __restrict__ dst, int s2r, int s2w,
                                       int m2) {
    cpx v[8];
#pragma unroll
    for (int t = 0; t < 8; ++t) v[t] = cup(src[s2r ^ (9 * t)]);
    twiddle8<S>(v, (float)S * (TWO_PI_F / 512.0f) * (float)m2);
    dft8<S>(v);
#pragma unroll
    for (int t = 0; t < 8; ++t) dst[s2w ^ (9 * t)] = cpk(v[t]);
}

template <int S>
__device__ __forceinline__ void stage3(const h2* __restrict__ src,
                                       h2* __restrict__ dst, int s3r, int s3w,
                                       int m3) {
    cpx v[8];
#pragma unroll
    for (int t = 0; t < 8; ++t) v[t] = cup(src[s3r ^ t]);
    twiddle8<S>(v, (float)S * (TWO_PI_F / 4096.0f) * (float)m3);
    dft8<S>(v);
    h2* __restrict__ pw = dst + s3w;
#pragma unroll
    for (int t = 0; t < 8; ++t) pw[512 * t] = cpk(v[t]);
}

// ---------------------------------------------------------------------------
// Kernel 1: blocks 0..16 -> gk[k]; blocks 17..33 -> htab (exact fp32 h).
// ---------------------------------------------------------------------------
__global__ __launch_bounds__(256, 2) void tables_kernel(
    const float* __restrict__ kin,
    const float* __restrict__ gw1, const float* __restrict__ gb1,
    const float* __restrict__ gw2, const float* __restrict__ gb2,
    const float* __restrict__ gw3, const float* __restrict__ gb3,
    const float* __restrict__ hw1, const float* __restrict__ hb1,
    const float* __restrict__ hw2, const float* __restrict__ hb2,
    const float* __restrict__ hw3, const float* __restrict__ hb3,
    cpx* __restrict__ gk_out, float* __restrict__ htab) {
    __shared__ __align__(16) float w2[4096];
    __shared__ float w1[64], b1[64], b2[64], w3a[64], w3b[64];
    __shared__ float b3a, b3b;
    const int tid = threadIdx.x;
    const bool isg = blockIdx.x < 17;
    const float* W1 = isg ? gw1 : hw1;
    const float* B1 = isg ? gb1 : hb1;
    const float* W2 = isg ? gw2 : hw2;
    const float* B2 = isg ? gb2 : hb2;
    for (int i = tid; i < 4096; i += 256) w2[i] = W2[i];
    if (tid < 64) {
        w1[tid] = W1[tid];
        b1[tid] = B1[tid];
        b2[tid] = B2[tid];
        if (isg) {
            w3a[tid] = gw3[tid * 2 + 0];
            w3b[tid] = gw3[tid * 2 + 1];
        } else {
            w3a[tid] = hw3[tid];
            w3b[tid] = 0.0f;
        }
    }
    if (tid == 0) {
        b3a = isg ? gb3[0] : hb3[0];
        b3b = isg ? gb3[1] : 0.0f;
    }
    __syncthreads();
    const int idx = (isg ? blockIdx.x : blockIdx.x - 17) * 256 + tid;
    if (idx >= 4097) return;
    const float x = isg ? kin[idx] : (-8.0f + (float)idx * (16.0f / 4096.0f));
    float acc[64];
#pragma unroll
    for (int i = 0; i < 64; ++i) acc[i] = b2[i];
#pragma unroll 2
    for (int j = 0; j < 64; ++j) {
        float h1 = elu(fmaf(x, w1[j], b1[j]));
        const float4* wr = (const float4*)&w2[j * 64];
#pragma unroll
        for (int q = 0; q < 16; ++q) {
            float4 wv = wr[q];
            acc[q * 4 + 0] = fmaf(h1, wv.x, acc[q * 4 + 0]);
            acc[q * 4 + 1] = fmaf(h1, wv.y, acc[q * 4 + 1]);
            acc[q * 4 + 2] = fmaf(h1, wv.z, acc[q * 4 + 2]);
            acc[q * 4 + 3] = fmaf(h1, wv.w, acc[q * 4 + 3]);
        }
    }
    float oa = b3a, ob = b3b;
#pragma unroll
    for (int i = 0; i < 64; ++i) {
        float h2v = elu(acc[i]);
        oa = fmaf(h2v, w3a[i], oa);
        ob = fmaf(h2v, w3b[i], ob);
    }
    if (isg) gk_out[idx] = cpx{oa, ob};
    else htab[idx] = oa;
}

// ---------------------------------------------------------------------------
// Kernel 1b: ab[k] — basis evaluation of the bilinear spectral map.
// Zi[k] = A*Zk + B*conj(Z[4096-k]), invn folded in.
// ---------------------------------------------------------------------------
__device__ __forceinline__ cpx spectral_eval(cpx Zk, cpx Zc, cpx w,
                                             cpx gkk, cpx gkm) {
    const cpx s = cadd(Zk, Zc);
    const cpx d = csub(Zk, Zc);
    const cpx wd = cmul(w, d);
    const cpx huh{0.5f * (s.x + wd.y), 0.5f * (s.y - wd.x)};
    const cpx Zr = cconj(Zc);
    const cpx Zkc = cconj(Zk);
    const cpx s2v = cadd(Zr, Zkc);
    const cpx d2v = csub(Zr, Zkc);
    const cpx wr{-w.x, w.y};
    const cpx wd2 = cmul(wr, d2v);
    const cpx huhr{0.5f * (s2v.x + wd2.y), 0.5f * (s2v.y - wd2.x)};
    const cpx Yk = cmul(gkk, huh);
    const cpx Yrc = cconj(cmul(gkm, huhr));
    const cpx E = cscale(0.5f, cadd(Yk, Yrc));
    const cpx D = cscale(0.5f, csub(Yk, Yrc));
    const cpx O = cmul(cconj(w), D);
    return cpx{E.x - O.y, E.y + O.x};
}

__global__ __launch_bounds__(256, 2) void ab_kernel(
    const cpx* __restrict__ gk, float4* __restrict__ ab) {
    const int k = blockIdx.x * 256 + threadIdx.x;   // 0..4095
    const float invn = 1.0f / 4096.0f;
    cpx w;
    {
        float ang = -TWO_PI_F * (float)k / 8192.0f;
        __sincosf(ang, &w.y, &w.x);
    }
    const cpx gkk = gk[k];
    const cpx gkm = gk[4096 - k];
    const cpx A = spectral_eval(cpx{1.0f, 0.0f}, cpx{0.0f, 0.0f}, w, gkk, gkm);
    const cpx B = spectral_eval(cpx{0.0f, 0.0f}, cpx{1.0f, 0.0f}, w, gkk, gkm);
    ab[k] = float4{A.x * invn, A.y * invn, B.x * invn, B.y * invn};
}

// ---------------------------------------------------------------------------
// Kernel 2: one 512-thread block per row, fp16x2 LDS (32KB total).
// fusedS0->A, S1 A->B, S2 B->A, S3 A->B, spectral+invS0 B->A,
// S1 A->B, S2 B->A(swz3), S3g A->GLOBAL coalesced (relabeled).
// ---------------------------------------------------------------------------
__global__ __launch_bounds__(512, 4) void morp_main(
    const float* __restrict__ u, const float* __restrict__ htab,
    const float4* __restrict__ ab, float* __restrict__ out) {
    __shared__ __align__(16) h2 bufA[4096];
    __shared__ __align__(16) h2 bufB[4096];
    const int tid = threadIdx.x;
    const int row = blockIdx.x;

    // ---- precomputed swizzled bases (once per thread)
    const int w3c = (tid >> 6) & 7;                           // wave id
    const int s0 = swz(tid);                                  // +512t
    const int b1 = (tid & 63) + 512 * (tid >> 6);
    const int s1 = b1 ^ ((b1 >> 3) & 7);                      // ^68t
    const int b2 = (tid & 7) + 64 * (tid >> 3);
    const int s2 = b2 ^ (((tid >> 3) & 7) << 2);              // ^9t
    const int b3 = 8 * (tid & 7) + 64 * (tid >> 3);
    const int s3r = b3 ^ (tid & 7) ^ (((tid >> 3) & 7) << 2); // ^t
    const int m3 = (tid >> 6) + 8 * ((tid >> 3) & 7) + 64 * (tid & 7);
    const int s3w = swz(m3);                                  // +512t
    // relabeled inverse-S3: thread tid runs butterfly q = m3 (involution);
    // reads the swz3 layout (swz ^ digit3), twiddle index m3(q)=tid.
    const int bq = 8 * (m3 & 7) + 64 * (m3 >> 3);
    const int s3g = bq ^ (m3 & 7) ^ (((m3 >> 3) & 7) << 2) ^ ((m3 >> 6) & 7);
    const int sm = swz(4096 - tid);                           // mirror: -512c
    const int k4 = tid >> 6;
    const int m2 = (tid >> 6) + 8 * ((tid >> 3) & 7);

    // ---- fused table-lerp + forward stage 0 (DFT8 over t4) -> bufA
    {
        const float2* urow2 = (const float2*)(u + (size_t)row * 8192);
        cpx v[8];
#pragma unroll
        for (int t = 0; t < 8; ++t) {
            const float2 uv = urow2[tid + 512 * t];
            float t0 = fmaf(uv.x, 256.0f, 2048.0f);
            t0 = fminf(fmaxf(t0, 0.0f), 4095.0f);
            const float fi0 = floorf(t0);
            const int i0 = (int)fi0;
            const float h00 = htab[i0], h01 = htab[i0 + 1];
            float t1 = fmaf(uv.y, 256.0f, 2048.0f);
            t1 = fminf(fmaxf(t1, 0.0f), 4095.0f);
            const float fi1 = floorf(t1);
            const int i1 = (int)fi1;
            const float h10 = htab[i1], h11 = htab[i1 + 1];
            v[t] = cpx{fmaf(t0 - fi0, h01 - h00, h00),
                       fmaf(t1 - fi1, h11 - h10, h10)};
        }
        dft8<-1>(v);
        h2* __restrict__ p = bufA + s0;
#pragma unroll
        for (int t = 0; t < 8; ++t) p[512 * t] = cpk(v[t]);
    }
    __syncthreads();
    stage1<-1>(bufA, bufB, s1, k4);
    __syncthreads();
    stage2<-1>(bufB, bufA, s2, s2, m2);
    __syncthreads();
    stage3<-1>(bufA, bufB, s3r, s3w, m3);
    __syncthreads();

    // ---- fused spectral (bilinear A/B) + inverse stage 0: B -> A
    {
        cpx zres[8];
        const h2* __restrict__ pk = bufB + s0;
        const int c0mir = (tid == 0) ? 0 : sm;
#pragma unroll
        for (int c = 0; c < 8; ++c) {
            const int k = tid + 512 * c;
            const float4 abv = ab[k];
            const cpx Zk = cup(pk[512 * c]);
            const cpx Zc = cconj(cup(bufB[c == 0 ? c0mir : (sm - 512 * c)]));
            const cpx az = cmul(cpx{abv.x, abv.y}, Zk);
            const cpx bz = cmul(cpx{abv.z, abv.w}, Zc);
            zres[c] = cadd(az, bz);
        }
        dft8<1>(zres);
        h2* __restrict__ pw = bufA + s0;
#pragma unroll
        for (int c = 0; c < 8; ++c) pw[512 * c] = cpk(zres[c]);
    }
    __syncthreads();
    stage1<1>(bufA, bufB, s1, k4);
    __syncthreads();
    stage2<1>(bufB, bufA, s2, s2 ^ w3c, m2);   // write generation in swz3
    __syncthreads();

    // ---- inverse S3, relabeled q = m3: read bufA (swz3), twiddle index tid,
    // write GLOBAL coalesced at n = tid + 512t. No copy-out.
    {
        cpx v[8];
#pragma unroll
        for (int t = 0; t < 8; ++t) v[t] = cup(bufA[s3g ^ t]);
        twiddle8<1>(v, (TWO_PI_F / 4096.0f) * (float)tid);
        dft8<1>(v);
        cpx* orow = (cpx*)(out + (size_t)row * 8192);
#pragma unroll
        for (int t = 0; t < 8; ++t) orow[tid + 512 * t] = v[t];
    }
}

extern "C" void kernel_launch(void* const* d_in, const int* in_sizes, int n_in,
                              void* d_out, int out_size, void* d_ws, size_t ws_size,
                              hipStream_t stream) {
    const float* u   = (const float*)d_in[0];
    const float* kin = (const float*)d_in[1];
    const float* hw1 = (const float*)d_in[2];
    const float* hb1 = (const float*)d_in[3];
    const float* hw2 = (const float*)d_in[4];
    const float* hb2 = (const float*)d_in[5];
    const float* hw3 = (const float*)d_in[6];
    const float* hb3 = (const float*)d_in[7];
    const float* gw1 = (const float*)d_in[8];
    const float* gb1 = (const float*)d_in[9];
    const float* gw2 = (const float*)d_in[10];
    const float* gb2 = (const float*)d_in[11];
    const float* gw3 = (const float*)d_in[12];
    const float* gb3 = (const float*)d_in[13];

    cpx* gk = (cpx*)d_ws;                               // 4097*8 = 32776 B
    float* htab = (float*)((char*)d_ws + 32832);        // 4097*4 = 16388 B
    float4* ab = (float4*)((char*)d_ws + 49280);        // 4096*16 = 65536 B
    tables_kernel<<<34, 256, 0, stream>>>(kin, gw1, gb1, gw2, gb2, gw3, gb3,
                                          hw1, hb1, hw2, hb2, hw3, hb3,
                                          gk, htab);
    ab_kernel<<<16, 256, 0, stream>>>(gk, ab);
    morp_main<<<2048, 512, 0, stream>>>(u, htab, ab, (float*)d_out);
}

// Round 20
// 58.809 us; speedup vs baseline: 1.3365x; 1.2649x over previous
//
#include <hip/hip_runtime.h>
#include <hip/hip_bf16.h>
#include <cstddef>

// ---------------------------------------------------------------------------
// MORP: Lu = irfft( g(k) * rfft( h(u) ) ), h/g tiny MLPs (1->64->64->{1,2}, ELU)
// B=2048 rows, N=8192, M=4097, W=64.
// Round 20 = Round 19 morp_main (validated, ~50us/dispatch) + FAST PREAMBLE:
// wall(74) - morp(50) = 24us was tables_kernel (34 blocks, 1 wave/SIMD,
// latency-bound serial MLP) + ab + gaps. New mlp_tables_kernel: ONE WAVE PER
// POINT (lane n = output channel; 64-step j loop of LDS-broadcast h1 x
// conflict-free w2[j][n]; shfl_xor reduce for the final dot), 2050 blocks ->
// 8 blocks/CU, latency hidden. ab_kernel and morp_main byte-identical to r19.
// ---------------------------------------------------------------------------

#define TWO_PI_F 6.28318530717958647693f

struct __align__(8) cpx { float x, y; };
typedef __fp16 h2 __attribute__((ext_vector_type(2)));

__device__ __forceinline__ h2 cpk(cpx a) {
    return __builtin_amdgcn_cvt_pkrtz(a.x, a.y);
}
__device__ __forceinline__ cpx cup(h2 p) {
    return cpx{(float)p.x, (float)p.y};
}

__device__ __forceinline__ cpx cmul(cpx a, cpx b) {
    return cpx{fmaf(a.x, b.x, -a.y * b.y), fmaf(a.x, b.y, a.y * b.x)};
}
__device__ __forceinline__ cpx cadd(cpx a, cpx b) { return cpx{a.x + b.x, a.y + b.y}; }
__device__ __forceinline__ cpx csub(cpx a, cpx b) { return cpx{a.x - b.x, a.y - b.y}; }
__device__ __forceinline__ cpx cscale(float s, cpx a) { return cpx{s * a.x, s * a.y}; }
__device__ __forceinline__ cpx cconj(cpx a) { return cpx{a.x, -a.y}; }
template <int S>
__device__ __forceinline__ cpx crot(cpx z) {   // multiply by S<0 ? -i : +i
    return (S < 0) ? cpx{z.y, -z.x} : cpx{-z.y, z.x};
}

__device__ __forceinline__ float elu(float x) {
    return x > 0.0f ? x : (__expf(x) - 1.0f);
}

// LDS index swizzle, b32-bank-tuned (bits 0-8 only; bits >=9 untouched).
__device__ __forceinline__ int swz(int i) {
    return i ^ ((i >> 3) & 7) ^ (((i >> 6) & 7) << 2);
}

// ---------------------------------------------------------------------------
// In-register 4/8-point DFT (natural order), sign S (-1 fwd, +1 inv).
// ---------------------------------------------------------------------------
template <int S>
__device__ __forceinline__ void dft4(cpx& x0, cpx& x1, cpx& x2, cpx& x3) {
    cpx e0 = cadd(x0, x2), e1 = csub(x0, x2);
    cpx o0 = cadd(x1, x3), o1 = crot<S>(csub(x1, x3));
    x0 = cadd(e0, o0);
    x1 = cadd(e1, o1);
    x2 = csub(e0, o0);
    x3 = csub(e1, o1);
}

template <int S>
__device__ __forceinline__ void dft8(cpx v[8]) {
    constexpr float r = 0.70710678118654752f;
    cpx E0 = v[0], E1 = v[2], E2 = v[4], E3 = v[6];
    cpx O0 = v[1], O1 = v[3], O2 = v[5], O3 = v[7];
    dft4<S>(E0, E1, E2, E3);
    dft4<S>(O0, O1, O2, O3);
    O1 = (S < 0) ? cpx{r * (O1.x + O1.y), r * (O1.y - O1.x)}
                 : cpx{r * (O1.x - O1.y), r * (O1.x + O1.y)};
    O2 = crot<S>(O2);
    O3 = (S < 0) ? cpx{r * (O3.y - O3.x), -r * (O3.x + O3.y)}
                 : cpx{-r * (O3.x + O3.y), r * (O3.x - O3.y)};
    v[0] = cadd(E0, O0);
    v[1] = cadd(E1, O1);
    v[2] = cadd(E2, O2);
    v[3] = cadd(E3, O3);
    v[4] = csub(E0, O0);
    v[5] = csub(E1, O1);
    v[6] = csub(E2, O2);
    v[7] = csub(E3, O3);
}

// Apply w^t, t=1..7, with w = cis(ang); depth-3 product tree.
template <int S>
__device__ __forceinline__ void twiddle8(cpx v[8], float ang) {
    cpx w;
    __sincosf(ang, &w.y, &w.x);
    const cpx t2 = cmul(w, w);
    const cpx t3 = cmul(t2, w);
    const cpx t4 = cmul(t2, t2);
    const cpx t5 = cmul(t4, w);
    const cpx t6 = cmul(t4, t2);
    const cpx t7 = cmul(t4, t3);
    v[1] = cmul(v[1], w);
    v[2] = cmul(v[2], t2);
    v[3] = cmul(v[3], t3);
    v[4] = cmul(v[4], t4);
    v[5] = cmul(v[5], t5);
    v[6] = cmul(v[6], t6);
    v[7] = cmul(v[7], t7);
}

// ---------------------------------------------------------------------------
// Radix-8 stages on fp16x2 LDS with precomputed swizzled bases.
// ---------------------------------------------------------------------------
template <int S>
__device__ __forceinline__ void stage1(const h2* __restrict__ src,
                                       h2* __restrict__ dst, int s1, int k4) {
    cpx v[8];
#pragma unroll
    for (int t = 0; t < 8; ++t) v[t] = cup(src[s1 ^ (68 * t)]);
    twiddle8<S>(v, (float)S * (TWO_PI_F / 64.0f) * (float)k4);
    dft8<S>(v);
#pragma unroll
    for (int t = 0; t < 8; ++t) dst[s1 ^ (68 * t)] = cpk(v[t]);
}

template <int S>
__device__ __forceinline__ void stage2(const h2* __restrict__ src,
                                       h2* __restrict__ dst, int s2r, int s2w,
                                       int m2) {
    cpx v[8];
#pragma unroll
    for (int t = 0; t < 8; ++t) v[t] = cup(src[s2r ^ (9 * t)]);
    twiddle8<S>(v, (float)S * (TWO_PI_F / 512.0f) * (float)m2);
    dft8<S>(v);
#pragma unroll
    for (int t = 0; t < 8; ++t) dst[s2w ^ (9 * t)] = cpk(v[t]);
}

template <int S>
__device__ __forceinline__ void stage3(const h2* __restrict__ src,
                                       h2* __restrict__ dst, int s3r, int s3w,
                                       int m3) {
    cpx v[8];
#pragma unroll
    for (int t = 0; t < 8; ++t) v[t] = cup(src[s3r ^ t]);
    twiddle8<S>(v, (float)S * (TWO_PI_F / 4096.0f) * (float)m3);
    dft8<S>(v);
    h2* __restrict__ pw = dst + s3w;
#pragma unroll
    for (int t = 0; t < 8; ++t) pw[512 * t] = cpk(v[t]);
}

// ---------------------------------------------------------------------------
// Kernel 1: wave-per-point MLP tables.
// blocks 0..1024   : htab points p = blk*4 + wave (h-MLP, exact fp32)
// blocks 1025..2049: gk   points p = (blk-1025)*4 + wave (g-MLP)
// Lane n owns output channel n; shfl-reduce for the final dot.
// ---------------------------------------------------------------------------
__global__ __launch_bounds__(256) void mlp_tables_kernel(
    const float* __restrict__ kin,
    const float* __restrict__ gw1, const float* __restrict__ gb1,
    const float* __restrict__ gw2, const float* __restrict__ gb2,
    const float* __restrict__ gw3, const float* __restrict__ gb3,
    const float* __restrict__ hw1, const float* __restrict__ hb1,
    const float* __restrict__ hw2, const float* __restrict__ hb2,
    const float* __restrict__ hw3, const float* __restrict__ hb3,
    cpx* __restrict__ gk_out, float* __restrict__ htab) {
    __shared__ __align__(16) float w2s[4096];
    __shared__ float w1s[64], b1s[64], b2s[64], w3as[64], w3bs[64];
    const int tid = threadIdx.x;
    const bool isH = blockIdx.x < 1025;
    const int pbase = (isH ? blockIdx.x : (blockIdx.x - 1025)) * 4;
    const float* W2 = isH ? hw2 : gw2;
    for (int i = tid; i < 1024; i += 256)
        ((float4*)w2s)[i] = ((const float4*)W2)[i];
    if (tid < 64) {
        w1s[tid] = isH ? hw1[tid] : gw1[tid];
        b1s[tid] = isH ? hb1[tid] : gb1[tid];
        b2s[tid] = isH ? hb2[tid] : gb2[tid];
        w3as[tid] = isH ? hw3[tid] : gw3[2 * tid];
        w3bs[tid] = isH ? 0.0f : gw3[2 * tid + 1];
    }
    __syncthreads();
    const int wv = tid >> 6, ln = tid & 63;
    const int p = pbase + wv;
    if (p > 4096) return;
    const float x = isH ? (-8.0f + (float)p * (16.0f / 4096.0f)) : kin[p];
    float acc = b2s[ln];
#pragma unroll 8
    for (int j = 0; j < 64; ++j) {
        const float h1 = elu(fmaf(x, w1s[j], b1s[j]));
        acc = fmaf(h1, w2s[j * 64 + ln], acc);
    }
    const float e = elu(acc);
    float oa = e * w3as[ln];
    float ob = e * w3bs[ln];
#pragma unroll
    for (int s = 1; s < 64; s <<= 1) {
        oa += __shfl_xor(oa, s, 64);
        ob += __shfl_xor(ob, s, 64);
    }
    if (ln == 0) {
        if (isH) htab[p] = oa + hb3[0];
        else gk_out[p] = cpx{oa + gb3[0], ob + gb3[1]};
    }
}

// ---------------------------------------------------------------------------
// Kernel 1b: ab[k] — basis evaluation of the bilinear spectral map.
// Zi[k] = A*Zk + B*conj(Z[4096-k]), invn folded in.
// ---------------------------------------------------------------------------
__device__ __forceinline__ cpx spectral_eval(cpx Zk, cpx Zc, cpx w,
                                             cpx gkk, cpx gkm) {
    const cpx s = cadd(Zk, Zc);
    const cpx d = csub(Zk, Zc);
    const cpx wd = cmul(w, d);
    const cpx huh{0.5f * (s.x + wd.y), 0.5f * (s.y - wd.x)};
    const cpx Zr = cconj(Zc);
    const cpx Zkc = cconj(Zk);
    const cpx s2v = cadd(Zr, Zkc);
    const cpx d2v = csub(Zr, Zkc);
    const cpx wr{-w.x, w.y};
    const cpx wd2 = cmul(wr, d2v);
    const cpx huhr{0.5f * (s2v.x + wd2.y), 0.5f * (s2v.y - wd2.x)};
    const cpx Yk = cmul(gkk, huh);
    const cpx Yrc = cconj(cmul(gkm, huhr));
    const cpx E = cscale(0.5f, cadd(Yk, Yrc));
    const cpx D = cscale(0.5f, csub(Yk, Yrc));
    const cpx O = cmul(cconj(w), D);
    return cpx{E.x - O.y, E.y + O.x};
}

__global__ __launch_bounds__(256, 2) void ab_kernel(
    const cpx* __restrict__ gk, float4* __restrict__ ab) {
    const int k = blockIdx.x * 256 + threadIdx.x;   // 0..4095
    const float invn = 1.0f / 4096.0f;
    cpx w;
    {
        float ang = -TWO_PI_F * (float)k / 8192.0f;
        __sincosf(ang, &w.y, &w.x);
    }
    const cpx gkk = gk[k];
    const cpx gkm = gk[4096 - k];
    const cpx A = spectral_eval(cpx{1.0f, 0.0f}, cpx{0.0f, 0.0f}, w, gkk, gkm);
    const cpx B = spectral_eval(cpx{0.0f, 0.0f}, cpx{1.0f, 0.0f}, w, gkk, gkm);
    ab[k] = float4{A.x * invn, A.y * invn, B.x * invn, B.y * invn};
}

// ---------------------------------------------------------------------------
// Kernel 2: one 512-thread block per row, fp16x2 LDS (32KB total).
// fusedS0->A, S1 A->B, S2 B->A, S3 A->B, spectral+invS0 B->A,
// S1 A->B, S2 B->A(swz3), S3g A->GLOBAL coalesced (relabeled).
// Byte-identical to round 19 (validated: 50us, absmax 0.375).
// ---------------------------------------------------------------------------
__global__ __launch_bounds__(512, 4) void morp_main(
    const float* __restrict__ u, const float* __restrict__ htab,
    const float4* __restrict__ ab, float* __restrict__ out) {
    __shared__ __align__(16) h2 bufA[4096];
    __shared__ __align__(16) h2 bufB[4096];
    const int tid = threadIdx.x;
    const int row = blockIdx.x;

    // ---- precomputed swizzled bases (once per thread)
    const int w3c = (tid >> 6) & 7;                           // wave id
    const int s0 = swz(tid);                                  // +512t
    const int b1 = (tid & 63) + 512 * (tid >> 6);
    const int s1 = b1 ^ ((b1 >> 3) & 7);                      // ^68t
    const int b2 = (tid & 7) + 64 * (tid >> 3);
    const int s2 = b2 ^ (((tid >> 3) & 7) << 2);              // ^9t
    const int b3 = 8 * (tid & 7) + 64 * (tid >> 3);
    const int s3r = b3 ^ (tid & 7) ^ (((tid >> 3) & 7) << 2); // ^t
    const int m3 = (tid >> 6) + 8 * ((tid >> 3) & 7) + 64 * (tid & 7);
    const int s3w = swz(m3);                                  // +512t
    // relabeled inverse-S3: thread tid runs butterfly q = m3 (involution);
    // reads the swz3 layout (swz ^ digit3), twiddle index m3(q)=tid.
    const int bq = 8 * (m3 & 7) + 64 * (m3 >> 3);
    const int s3g = bq ^ (m3 & 7) ^ (((m3 >> 3) & 7) << 2) ^ ((m3 >> 6) & 7);
    const int sm = swz(4096 - tid);                           // mirror: -512c
    const int k4 = tid >> 6;
    const int m2 = (tid >> 6) + 8 * ((tid >> 3) & 7);

    // ---- fused table-lerp + forward stage 0 (DFT8 over t4) -> bufA
    {
        const float2* urow2 = (const float2*)(u + (size_t)row * 8192);
        cpx v[8];
#pragma unroll
        for (int t = 0; t < 8; ++t) {
            const float2 uv = urow2[tid + 512 * t];
            float t0 = fmaf(uv.x, 256.0f, 2048.0f);
            t0 = fminf(fmaxf(t0, 0.0f), 4095.0f);
            const float fi0 = floorf(t0);
            const int i0 = (int)fi0;
            const float h00 = htab[i0], h01 = htab[i0 + 1];
            float t1 = fmaf(uv.y, 256.0f, 2048.0f);
            t1 = fminf(fmaxf(t1, 0.0f), 4095.0f);
            const float fi1 = floorf(t1);
            const int i1 = (int)fi1;
            const float h10 = htab[i1], h11 = htab[i1 + 1];
            v[t] = cpx{fmaf(t0 - fi0, h01 - h00, h00),
                       fmaf(t1 - fi1, h11 - h10, h10)};
        }
        dft8<-1>(v);
        h2* __restrict__ p = bufA + s0;
#pragma unroll
        for (int t = 0; t < 8; ++t) p[512 * t] = cpk(v[t]);
    }
    __syncthreads();
    stage1<-1>(bufA, bufB, s1, k4);
    __syncthreads();
    stage2<-1>(bufB, bufA, s2, s2, m2);
    __syncthreads();
    stage3<-1>(bufA, bufB, s3r, s3w, m3);
    __syncthreads();

    // ---- fused spectral (bilinear A/B) + inverse stage 0: B -> A
    {
        cpx zres[8];
        const h2* __restrict__ pk = bufB + s0;
        const int c0mir = (tid == 0) ? 0 : sm;
#pragma unroll
        for (int c = 0; c < 8; ++c) {
            const int k = tid + 512 * c;
            const float4 abv = ab[k];
            const cpx Zk = cup(pk[512 * c]);
            const cpx Zc = cconj(cup(bufB[c == 0 ? c0mir : (sm - 512 * c)]));
            const cpx az = cmul(cpx{abv.x, abv.y}, Zk);
            const cpx bz = cmul(cpx{abv.z, abv.w}, Zc);
            zres[c] = cadd(az, bz);
        }
        dft8<1>(zres);
        h2* __restrict__ pw = bufA + s0;
#pragma unroll
        for (int c = 0; c < 8; ++c) pw[512 * c] = cpk(zres[c]);
    }
    __syncthreads();
    stage1<1>(bufA, bufB, s1, k4);
    __syncthreads();
    stage2<1>(bufB, bufA, s2, s2 ^ w3c, m2);   // write generation in swz3
    __syncthreads();

    // ---- inverse S3, relabeled q = m3: read bufA (swz3), twiddle index tid,
    // write GLOBAL coalesced at n = tid + 512t. No copy-out.
    {
        cpx v[8];
#pragma unroll
        for (int t = 0; t < 8; ++t) v[t] = cup(bufA[s3g ^ t]);
        twiddle8<1>(v, (TWO_PI_F / 4096.0f) * (float)tid);
        dft8<1>(v);
        cpx* orow = (cpx*)(out + (size_t)row * 8192);
#pragma unroll
        for (int t = 0; t < 8; ++t) orow[tid + 512 * t] = v[t];
    }
}

extern "C" void kernel_launch(void* const* d_in, const int* in_sizes, int n_in,
                              void* d_out, int out_size, void* d_ws, size_t ws_size,
                              hipStream_t stream) {
    const float* u   = (const float*)d_in[0];
    const float* kin = (const float*)d_in[1];
    const float* hw1 = (const float*)d_in[2];
    const float* hb1 = (const float*)d_in[3];
    const float* hw2 = (const float*)d_in[4];
    const float* hb2 = (const float*)d_in[5];
    const float* hw3 = (const float*)d_in[6];
    const float* hb3 = (const float*)d_in[7];
    const float* gw1 = (const float*)d_in[8];
    const float* gb1 = (const float*)d_in[9];
    const float* gw2 = (const float*)d_in[10];
    const float* gb2 = (const float*)d_in[11];
    const float* gw3 = (const float*)d_in[12];
    const float* gb3 = (const float*)d_in[13];

    cpx* gk = (cpx*)d_ws;                               // 4097*8 = 32776 B
    float* htab = (float*)((char*)d_ws + 32832);        // 4097*4 = 16388 B
    float4* ab = (float4*)((char*)d_ws + 49280);        // 4096*16 = 65536 B
    mlp_tables_kernel<<<2050, 256, 0, stream>>>(
        kin, gw1, gb1, gw2, gb2, gw3, gb3,
        hw1, hb1, hw2, hb2, hw3, hb3, gk, htab);
    ab_kernel<<<16, 256, 0, stream>>>(gk, ab);
    morp_main<<<2048, 512, 0, stream>>>(u, htab, ab, (float*)d_out);
}

// Round 22
// 58.486 us; speedup vs baseline: 1.3439x; 1.0055x over previous
//
#include <hip/hip_runtime.h>
#include <hip/hip_bf16.h>
#include <cstddef>

// ---------------------------------------------------------------------------
// MORP: Lu = irfft( g(k) * rfft( h(u) ) ), h/g tiny MLPs (1->64->64->{1,2}, ELU)
// B=2048 rows, N=8192, M=4097, W=64.
// Round 22 = Round 20 + ONLY the two provably-safe barrier elisions.
// r21's failure mechanism (found): fwd-S3's WRITE is a cross-block scatter
// (s3w+512t); without the S2->S3 barrier a fast wave's S3 overwrites bufB
// blocks that slow waves are still reading in S2. That barrier is RESTORED.
// Safe elisions kept: fwd S1->S2 and inv S1->S2 — between full barriers,
// bufA block-w (fwd) and bufB block-w (inv) are touched ONLY by wave w, and
// same-wave DS ops complete in order. 7 -> 5 barriers.
// ---------------------------------------------------------------------------

#define TWO_PI_F 6.28318530717958647693f

struct __align__(8) cpx { float x, y; };
typedef __fp16 h2 __attribute__((ext_vector_type(2)));

__device__ __forceinline__ h2 cpk(cpx a) {
    return __builtin_amdgcn_cvt_pkrtz(a.x, a.y);
}
__device__ __forceinline__ cpx cup(h2 p) {
    return cpx{(float)p.x, (float)p.y};
}

__device__ __forceinline__ cpx cmul(cpx a, cpx b) {
    return cpx{fmaf(a.x, b.x, -a.y * b.y), fmaf(a.x, b.y, a.y * b.x)};
}
__device__ __forceinline__ cpx cadd(cpx a, cpx b) { return cpx{a.x + b.x, a.y + b.y}; }
__device__ __forceinline__ cpx csub(cpx a, cpx b) { return cpx{a.x - b.x, a.y - b.y}; }
__device__ __forceinline__ cpx cscale(float s, cpx a) { return cpx{s * a.x, s * a.y}; }
__device__ __forceinline__ cpx cconj(cpx a) { return cpx{a.x, -a.y}; }
template <int S>
__device__ __forceinline__ cpx crot(cpx z) {   // multiply by S<0 ? -i : +i
    return (S < 0) ? cpx{z.y, -z.x} : cpx{-z.y, z.x};
}

__device__ __forceinline__ float elu(float x) {
    return x > 0.0f ? x : (__expf(x) - 1.0f);
}

// LDS index swizzle, b32-bank-tuned (bits 0-8 only; bits >=9 untouched).
__device__ __forceinline__ int swz(int i) {
    return i ^ ((i >> 3) & 7) ^ (((i >> 6) & 7) << 2);
}

// ---------------------------------------------------------------------------
// In-register 4/8-point DFT (natural order), sign S (-1 fwd, +1 inv).
// ---------------------------------------------------------------------------
template <int S>
__device__ __forceinline__ void dft4(cpx& x0, cpx& x1, cpx& x2, cpx& x3) {
    cpx e0 = cadd(x0, x2), e1 = csub(x0, x2);
    cpx o0 = cadd(x1, x3), o1 = crot<S>(csub(x1, x3));
    x0 = cadd(e0, o0);
    x1 = cadd(e1, o1);
    x2 = csub(e0, o0);
    x3 = csub(e1, o1);
}

template <int S>
__device__ __forceinline__ void dft8(cpx v[8]) {
    constexpr float r = 0.70710678118654752f;
    cpx E0 = v[0], E1 = v[2], E2 = v[4], E3 = v[6];
    cpx O0 = v[1], O1 = v[3], O2 = v[5], O3 = v[7];
    dft4<S>(E0, E1, E2, E3);
    dft4<S>(O0, O1, O2, O3);
    O1 = (S < 0) ? cpx{r * (O1.x + O1.y), r * (O1.y - O1.x)}
                 : cpx{r * (O1.x - O1.y), r * (O1.x + O1.y)};
    O2 = crot<S>(O2);
    O3 = (S < 0) ? cpx{r * (O3.y - O3.x), -r * (O3.x + O3.y)}
                 : cpx{-r * (O3.x + O3.y), r * (O3.x - O3.y)};
    v[0] = cadd(E0, O0);
    v[1] = cadd(E1, O1);
    v[2] = cadd(E2, O2);
    v[3] = cadd(E3, O3);
    v[4] = csub(E0, O0);
    v[5] = csub(E1, O1);
    v[6] = csub(E2, O2);
    v[7] = csub(E3, O3);
}

// Apply w^t, t=1..7, with w = cis(ang); depth-3 product tree.
template <int S>
__device__ __forceinline__ void twiddle8(cpx v[8], float ang) {
    cpx w;
    __sincosf(ang, &w.y, &w.x);
    const cpx t2 = cmul(w, w);
    const cpx t3 = cmul(t2, w);
    const cpx t4 = cmul(t2, t2);
    const cpx t5 = cmul(t4, w);
    const cpx t6 = cmul(t4, t2);
    const cpx t7 = cmul(t4, t3);
    v[1] = cmul(v[1], w);
    v[2] = cmul(v[2], t2);
    v[3] = cmul(v[3], t3);
    v[4] = cmul(v[4], t4);
    v[5] = cmul(v[5], t5);
    v[6] = cmul(v[6], t6);
    v[7] = cmul(v[7], t7);
}

// ---------------------------------------------------------------------------
// Radix-8 stages on fp16x2 LDS with precomputed swizzled bases.
// ---------------------------------------------------------------------------
template <int S>
__device__ __forceinline__ void stage1(const h2* __restrict__ src,
                                       h2* __restrict__ dst, int s1, int k4) {
    cpx v[8];
#pragma unroll
    for (int t = 0; t < 8; ++t) v[t] = cup(src[s1 ^ (68 * t)]);
    twiddle8<S>(v, (float)S * (TWO_PI_F / 64.0f) * (float)k4);
    dft8<S>(v);
#pragma unroll
    for (int t = 0; t < 8; ++t) dst[s1 ^ (68 * t)] = cpk(v[t]);
}

template <int S>
__device__ __forceinline__ void stage2(const h2* __restrict__ src,
                                       h2* __restrict__ dst, int s2r, int s2w,
                                       int m2) {
    cpx v[8];
#pragma unroll
    for (int t = 0; t < 8; ++t) v[t] = cup(src[s2r ^ (9 * t)]);
    twiddle8<S>(v, (float)S * (TWO_PI_F / 512.0f) * (float)m2);
    dft8<S>(v);
#pragma unroll
    for (int t = 0; t < 8; ++t) dst[s2w ^ (9 * t)] = cpk(v[t]);
}

template <int S>
__device__ __forceinline__ void stage3(const h2* __restrict__ src,
                                       h2* __restrict__ dst, int s3r, int s3w,
                                       int m3) {
    cpx v[8];
#pragma unroll
    for (int t = 0; t < 8; ++t) v[t] = cup(src[s3r ^ t]);
    twiddle8<S>(v, (float)S * (TWO_PI_F / 4096.0f) * (float)m3);
    dft8<S>(v);
    h2* __restrict__ pw = dst + s3w;
#pragma unroll
    for (int t = 0; t < 8; ++t) pw[512 * t] = cpk(v[t]);
}

// ---------------------------------------------------------------------------
// Kernel 1: wave-per-point MLP tables (validated r20).
// blocks 0..1024   : htab points p = blk*4 + wave (h-MLP, exact fp32)
// blocks 1025..2049: gk   points p = (blk-1025)*4 + wave (g-MLP)
// ---------------------------------------------------------------------------
__global__ __launch_bounds__(256) void mlp_tables_kernel(
    const float* __restrict__ kin,
    const float* __restrict__ gw1, const float* __restrict__ gb1,
    const float* __restrict__ gw2, const float* __restrict__ gb2,
    const float* __restrict__ gw3, const float* __restrict__ gb3,
    const float* __restrict__ hw1, const float* __restrict__ hb1,
    const float* __restrict__ hw2, const float* __restrict__ hb2,
    const float* __restrict__ hw3, const float* __restrict__ hb3,
    cpx* __restrict__ gk_out, float* __restrict__ htab) {
    __shared__ __align__(16) float w2s[4096];
    __shared__ float w1s[64], b1s[64], b2s[64], w3as[64], w3bs[64];
    const int tid = threadIdx.x;
    const bool isH = blockIdx.x < 1025;
    const int pbase = (isH ? blockIdx.x : (blockIdx.x - 1025)) * 4;
    const float* W2 = isH ? hw2 : gw2;
    for (int i = tid; i < 1024; i += 256)
        ((float4*)w2s)[i] = ((const float4*)W2)[i];
    if (tid < 64) {
        w1s[tid] = isH ? hw1[tid] : gw1[tid];
        b1s[tid] = isH ? hb1[tid] : gb1[tid];
        b2s[tid] = isH ? hb2[tid] : gb2[tid];
        w3as[tid] = isH ? hw3[tid] : gw3[2 * tid];
        w3bs[tid] = isH ? 0.0f : gw3[2 * tid + 1];
    }
    __syncthreads();
    const int wv = tid >> 6, ln = tid & 63;
    const int p = pbase + wv;
    if (p > 4096) return;
    const float x = isH ? (-8.0f + (float)p * (16.0f / 4096.0f)) : kin[p];
    float acc = b2s[ln];
#pragma unroll 8
    for (int j = 0; j < 64; ++j) {
        const float h1 = elu(fmaf(x, w1s[j], b1s[j]));
        acc = fmaf(h1, w2s[j * 64 + ln], acc);
    }
    const float e = elu(acc);
    float oa = e * w3as[ln];
    float ob = e * w3bs[ln];
#pragma unroll
    for (int s = 1; s < 64; s <<= 1) {
        oa += __shfl_xor(oa, s, 64);
        ob += __shfl_xor(ob, s, 64);
    }
    if (ln == 0) {
        if (isH) htab[p] = oa + hb3[0];
        else gk_out[p] = cpx{oa + gb3[0], ob + gb3[1]};
    }
}

// ---------------------------------------------------------------------------
// Kernel 1b: ab[k] — basis evaluation of the bilinear spectral map.
// Zi[k] = A*Zk + B*conj(Z[4096-k]), invn folded in.
// ---------------------------------------------------------------------------
__device__ __forceinline__ cpx spectral_eval(cpx Zk, cpx Zc, cpx w,
                                             cpx gkk, cpx gkm) {
    const cpx s = cadd(Zk, Zc);
    const cpx d = csub(Zk, Zc);
    const cpx wd = cmul(w, d);
    const cpx huh{0.5f * (s.x + wd.y), 0.5f * (s.y - wd.x)};
    const cpx Zr = cconj(Zc);
    const cpx Zkc = cconj(Zk);
    const cpx s2v = cadd(Zr, Zkc);
    const cpx d2v = csub(Zr, Zkc);
    const cpx wr{-w.x, w.y};
    const cpx wd2 = cmul(wr, d2v);
    const cpx huhr{0.5f * (s2v.x + wd2.y), 0.5f * (s2v.y - wd2.x)};
    const cpx Yk = cmul(gkk, huh);
    const cpx Yrc = cconj(cmul(gkm, huhr));
    const cpx E = cscale(0.5f, cadd(Yk, Yrc));
    const cpx D = cscale(0.5f, csub(Yk, Yrc));
    const cpx O = cmul(cconj(w), D);
    return cpx{E.x - O.y, E.y + O.x};
}

__global__ __launch_bounds__(256, 2) void ab_kernel(
    const cpx* __restrict__ gk, float4* __restrict__ ab) {
    const int k = blockIdx.x * 256 + threadIdx.x;   // 0..4095
    const float invn = 1.0f / 4096.0f;
    cpx w;
    {
        float ang = -TWO_PI_F * (float)k / 8192.0f;
        __sincosf(ang, &w.y, &w.x);
    }
    const cpx gkk = gk[k];
    const cpx gkm = gk[4096 - k];
    const cpx A = spectral_eval(cpx{1.0f, 0.0f}, cpx{0.0f, 0.0f}, w, gkk, gkm);
    const cpx B = spectral_eval(cpx{0.0f, 0.0f}, cpx{1.0f, 0.0f}, w, gkk, gkm);
    ab[k] = float4{A.x * invn, A.y * invn, B.x * invn, B.y * invn};
}

// ---------------------------------------------------------------------------
// Kernel 2: one 512-thread block per row, fp16x2 LDS (32KB total).
// 5 barriers: after S0, after fwd-S2 (protects S3 scatter), after fwd-S3,
// after spectral/invS0, after inv-S2 (protects relabeled S3g cross-block read).
// Elided (wave-confined, single-wave buffer-block ownership): fwd S1->S2,
// inv S1->S2.
// ---------------------------------------------------------------------------
__global__ __launch_bounds__(512, 4) void morp_main(
    const float* __restrict__ u, const float* __restrict__ htab,
    const float4* __restrict__ ab, float* __restrict__ out) {
    __shared__ __align__(16) h2 bufA[4096];
    __shared__ __align__(16) h2 bufB[4096];
    const int tid = threadIdx.x;
    const int row = blockIdx.x;

    // ---- precomputed swizzled bases (once per thread)
    const int w3c = (tid >> 6) & 7;                           // wave id
    const int s0 = swz(tid);                                  // +512t
    const int b1 = (tid & 63) + 512 * (tid >> 6);
    const int s1 = b1 ^ ((b1 >> 3) & 7);                      // ^68t
    const int b2 = (tid & 7) + 64 * (tid >> 3);
    const int s2 = b2 ^ (((tid >> 3) & 7) << 2);              // ^9t
    const int b3 = 8 * (tid & 7) + 64 * (tid >> 3);
    const int s3r = b3 ^ (tid & 7) ^ (((tid >> 3) & 7) << 2); // ^t
    const int m3 = (tid >> 6) + 8 * ((tid >> 3) & 7) + 64 * (tid & 7);
    const int s3w = swz(m3);                                  // +512t
    // relabeled inverse-S3: thread tid runs butterfly q = m3 (involution);
    // reads the swz3 layout (swz ^ digit3), twiddle index m3(q)=tid.
    const int bq = 8 * (m3 & 7) + 64 * (m3 >> 3);
    const int s3g = bq ^ (m3 & 7) ^ (((m3 >> 3) & 7) << 2) ^ ((m3 >> 6) & 7);
    const int sm = swz(4096 - tid);                           // mirror: -512c
    const int k4 = tid >> 6;
    const int m2 = (tid >> 6) + 8 * ((tid >> 3) & 7);

    // ---- fused table-lerp + forward stage 0 (DFT8 over t4) -> bufA
    {
        const float2* urow2 = (const float2*)(u + (size_t)row * 8192);
        cpx v[8];
#pragma unroll
        for (int t = 0; t < 8; ++t) {
            const float2 uv = urow2[tid + 512 * t];
            float t0 = fmaf(uv.x, 256.0f, 2048.0f);
            t0 = fminf(fmaxf(t0, 0.0f), 4095.0f);
            const float fi0 = floorf(t0);
            const int i0 = (int)fi0;
            const float h00 = htab[i0], h01 = htab[i0 + 1];
            float t1 = fmaf(uv.y, 256.0f, 2048.0f);
            t1 = fminf(fmaxf(t1, 0.0f), 4095.0f);
            const float fi1 = floorf(t1);
            const int i1 = (int)fi1;
            const float h10 = htab[i1], h11 = htab[i1 + 1];
            v[t] = cpx{fmaf(t0 - fi0, h01 - h00, h00),
                       fmaf(t1 - fi1, h11 - h10, h10)};
        }
        dft8<-1>(v);
        h2* __restrict__ p = bufA + s0;
#pragma unroll
        for (int t = 0; t < 8; ++t) p[512 * t] = cpk(v[t]);
    }
    __syncthreads();                       // cross-wave (S0 scatter)
    stage1<-1>(bufA, bufB, s1, k4);
    asm volatile("" ::: "memory");         // wave-confined handoff (safe)
    stage2<-1>(bufB, bufA, s2, s2, m2);
    __syncthreads();                       // protects S3's cross-block WRITE
    stage3<-1>(bufA, bufB, s3r, s3w, m3);
    __syncthreads();                       // cross-wave (S3 scatter + mirror)

    // ---- fused spectral (bilinear A/B) + inverse stage 0: B -> A
    {
        cpx zres[8];
        const h2* __restrict__ pk = bufB + s0;
        const int c0mir = (tid == 0) ? 0 : sm;
#pragma unroll
        for (int c = 0; c < 8; ++c) {
            const int k = tid + 512 * c;
            const float4 abv = ab[k];
            const cpx Zk = cup(pk[512 * c]);
            const cpx Zc = cconj(cup(bufB[c == 0 ? c0mir : (sm - 512 * c)]));
            const cpx az = cmul(cpx{abv.x, abv.y}, Zk);
            const cpx bz = cmul(cpx{abv.z, abv.w}, Zc);
            zres[c] = cadd(az, bz);
        }
        dft8<1>(zres);
        h2* __restrict__ pw = bufA + s0;
#pragma unroll
        for (int c = 0; c < 8; ++c) pw[512 * c] = cpk(zres[c]);
    }
    __syncthreads();                       // cross-wave (invS0 scatter)
    stage1<1>(bufA, bufB, s1, k4);
    asm volatile("" ::: "memory");         // wave-confined handoff (safe)
    stage2<1>(bufB, bufA, s2, s2 ^ w3c, m2);   // write generation in swz3
    __syncthreads();                       // cross-wave (relabeled S3g read)

    // ---- inverse S3, relabeled q = m3: read bufA (swz3), twiddle index tid,
    // write GLOBAL coalesced at n = tid + 512t. No copy-out.
    {
        cpx v[8];
#pragma unroll
        for (int t = 0; t < 8; ++t) v[t] = cup(bufA[s3g ^ t]);
        twiddle8<1>(v, (TWO_PI_F / 4096.0f) * (float)tid);
        dft8<1>(v);
        cpx* orow = (cpx*)(out + (size_t)row * 8192);
#pragma unroll
        for (int t = 0; t < 8; ++t) orow[tid + 512 * t] = v[t];
    }
}

extern "C" void kernel_launch(void* const* d_in, const int* in_sizes, int n_in,
                              void* d_out, int out_size, void* d_ws, size_t ws_size,
                              hipStream_t stream) {
    const float* u   = (const float*)d_in[0];
    const float* kin = (const float*)d_in[1];
    const float* hw1 = (const float*)d_in[2];
    const float* hb1 = (const float*)d_in[3];
    const float* hw2 = (const float*)d_in[4];
    const float* hb2 = (const float*)d_in[5];
    const float* hw3 = (const float*)d_in[6];
    const float* hb3 = (const float*)d_in[7];
    const float* gw1 = (const float*)d_in[8];
    const float* gb1 = (const float*)d_in[9];
    const float* gw2 = (const float*)d_in[10];
    const float* gb2 = (const float*)d_in[11];
    const float* gw3 = (const float*)d_in[12];
    const float* gb3 = (const float*)d_in[13];

    cpx* gk = (cpx*)d_ws;                               // 4097*8 = 32776 B
    float* htab = (float*)((char*)d_ws + 32832);        // 4097*4 = 16388 B
    float4* ab = (float4*)((char*)d_ws + 49280);        // 4096*16 = 65536 B
    mlp_tables_kernel<<<2050, 256, 0, stream>>>(
        kin, gw1, gb1, gw2, gb2, gw3, gb3,
        hw1, hb1, hw2, hb2, hw3, hb3, gk, htab);
    ab_kernel<<<16, 256, 0, stream>>>(gk, ab);
    morp_main<<<2048, 512, 0, stream>>>(u, htab, ab, (float*)d_out);
}

// Round 23
// 56.199 us; speedup vs baseline: 1.3986x; 1.0407x over previous
//
#include <hip/hip_runtime.h>
#include <hip/hip_bf16.h>
#include <cstddef>

// ---------------------------------------------------------------------------
// MORP: Lu = irfft( g(k) * rfft( h(u) ) ), h/g tiny MLPs (1->64->64->{1,2}, ELU)
// B=2048 rows, N=8192, M=4097, W=64.
// Round 23 = Round 22 morp_main (validated, ~50us) + PREAMBLE COLLAPSE:
// ab is the only consumer of gk, and ab[k] needs the pair (gk[k],gk[4096-k]).
// g-blocks now compute {k0,k1,4096-k0,4096-k1} (wave-per-point MLP), stash
// the 4 gk values in LDS, barrier, and threads 0-3 emit the ab entries via
// spectral_eval directly. ab_kernel launch deleted; gk never hits memory.
// Overlapping k coverage writes identical values (deterministic). morp_main
// byte-identical to r22 (5 barriers, fp16x2 LDS, bilinear spectral).
// ---------------------------------------------------------------------------

#define TWO_PI_F 6.28318530717958647693f

struct __align__(8) cpx { float x, y; };
typedef __fp16 h2 __attribute__((ext_vector_type(2)));

__device__ __forceinline__ h2 cpk(cpx a) {
    return __builtin_amdgcn_cvt_pkrtz(a.x, a.y);
}
__device__ __forceinline__ cpx cup(h2 p) {
    return cpx{(float)p.x, (float)p.y};
}

__device__ __forceinline__ cpx cmul(cpx a, cpx b) {
    return cpx{fmaf(a.x, b.x, -a.y * b.y), fmaf(a.x, b.y, a.y * b.x)};
}
__device__ __forceinline__ cpx cadd(cpx a, cpx b) { return cpx{a.x + b.x, a.y + b.y}; }
__device__ __forceinline__ cpx csub(cpx a, cpx b) { return cpx{a.x - b.x, a.y - b.y}; }
__device__ __forceinline__ cpx cscale(float s, cpx a) { return cpx{s * a.x, s * a.y}; }
__device__ __forceinline__ cpx cconj(cpx a) { return cpx{a.x, -a.y}; }
template <int S>
__device__ __forceinline__ cpx crot(cpx z) {   // multiply by S<0 ? -i : +i
    return (S < 0) ? cpx{z.y, -z.x} : cpx{-z.y, z.x};
}

__device__ __forceinline__ float elu(float x) {
    return x > 0.0f ? x : (__expf(x) - 1.0f);
}

// LDS index swizzle, b32-bank-tuned (bits 0-8 only; bits >=9 untouched).
__device__ __forceinline__ int swz(int i) {
    return i ^ ((i >> 3) & 7) ^ (((i >> 6) & 7) << 2);
}

// ---------------------------------------------------------------------------
// In-register 4/8-point DFT (natural order), sign S (-1 fwd, +1 inv).
// ---------------------------------------------------------------------------
template <int S>
__device__ __forceinline__ void dft4(cpx& x0, cpx& x1, cpx& x2, cpx& x3) {
    cpx e0 = cadd(x0, x2), e1 = csub(x0, x2);
    cpx o0 = cadd(x1, x3), o1 = crot<S>(csub(x1, x3));
    x0 = cadd(e0, o0);
    x1 = cadd(e1, o1);
    x2 = csub(e0, o0);
    x3 = csub(e1, o1);
}

template <int S>
__device__ __forceinline__ void dft8(cpx v[8]) {
    constexpr float r = 0.70710678118654752f;
    cpx E0 = v[0], E1 = v[2], E2 = v[4], E3 = v[6];
    cpx O0 = v[1], O1 = v[3], O2 = v[5], O3 = v[7];
    dft4<S>(E0, E1, E2, E3);
    dft4<S>(O0, O1, O2, O3);
    O1 = (S < 0) ? cpx{r * (O1.x + O1.y), r * (O1.y - O1.x)}
                 : cpx{r * (O1.x - O1.y), r * (O1.x + O1.y)};
    O2 = crot<S>(O2);
    O3 = (S < 0) ? cpx{r * (O3.y - O3.x), -r * (O3.x + O3.y)}
                 : cpx{-r * (O3.x + O3.y), r * (O3.x - O3.y)};
    v[0] = cadd(E0, O0);
    v[1] = cadd(E1, O1);
    v[2] = cadd(E2, O2);
    v[3] = cadd(E3, O3);
    v[4] = csub(E0, O0);
    v[5] = csub(E1, O1);
    v[6] = csub(E2, O2);
    v[7] = csub(E3, O3);
}

// Apply w^t, t=1..7, with w = cis(ang); depth-3 product tree.
template <int S>
__device__ __forceinline__ void twiddle8(cpx v[8], float ang) {
    cpx w;
    __sincosf(ang, &w.y, &w.x);
    const cpx t2 = cmul(w, w);
    const cpx t3 = cmul(t2, w);
    const cpx t4 = cmul(t2, t2);
    const cpx t5 = cmul(t4, w);
    const cpx t6 = cmul(t4, t2);
    const cpx t7 = cmul(t4, t3);
    v[1] = cmul(v[1], w);
    v[2] = cmul(v[2], t2);
    v[3] = cmul(v[3], t3);
    v[4] = cmul(v[4], t4);
    v[5] = cmul(v[5], t5);
    v[6] = cmul(v[6], t6);
    v[7] = cmul(v[7], t7);
}

// ---------------------------------------------------------------------------
// Radix-8 stages on fp16x2 LDS with precomputed swizzled bases.
// ---------------------------------------------------------------------------
template <int S>
__device__ __forceinline__ void stage1(const h2* __restrict__ src,
                                       h2* __restrict__ dst, int s1, int k4) {
    cpx v[8];
#pragma unroll
    for (int t = 0; t < 8; ++t) v[t] = cup(src[s1 ^ (68 * t)]);
    twiddle8<S>(v, (float)S * (TWO_PI_F / 64.0f) * (float)k4);
    dft8<S>(v);
#pragma unroll
    for (int t = 0; t < 8; ++t) dst[s1 ^ (68 * t)] = cpk(v[t]);
}

template <int S>
__device__ __forceinline__ void stage2(const h2* __restrict__ src,
                                       h2* __restrict__ dst, int s2r, int s2w,
                                       int m2) {
    cpx v[8];
#pragma unroll
    for (int t = 0; t < 8; ++t) v[t] = cup(src[s2r ^ (9 * t)]);
    twiddle8<S>(v, (float)S * (TWO_PI_F / 512.0f) * (float)m2);
    dft8<S>(v);
#pragma unroll
    for (int t = 0; t < 8; ++t) dst[s2w ^ (9 * t)] = cpk(v[t]);
}

template <int S>
__device__ __forceinline__ void stage3(const h2* __restrict__ src,
                                       h2* __restrict__ dst, int s3r, int s3w,
                                       int m3) {
    cpx v[8];
#pragma unroll
    for (int t = 0; t < 8; ++t) v[t] = cup(src[s3r ^ t]);
    twiddle8<S>(v, (float)S * (TWO_PI_F / 4096.0f) * (float)m3);
    dft8<S>(v);
    h2* __restrict__ pw = dst + s3w;
#pragma unroll
    for (int t = 0; t < 8; ++t) pw[512 * t] = cpk(v[t]);
}

// ---------------------------------------------------------------------------
// Bilinear spectral map basis evaluation (invn NOT folded here).
// Zi[k] = A*Zk + B*conj(Z[4096-k]).
// ---------------------------------------------------------------------------
__device__ __forceinline__ cpx spectral_eval(cpx Zk, cpx Zc, cpx w,
                                             cpx gkk, cpx gkm) {
    const cpx s = cadd(Zk, Zc);
    const cpx d = csub(Zk, Zc);
    const cpx wd = cmul(w, d);
    const cpx huh{0.5f * (s.x + wd.y), 0.5f * (s.y - wd.x)};
    const cpx Zr = cconj(Zc);
    const cpx Zkc = cconj(Zk);
    const cpx s2v = cadd(Zr, Zkc);
    const cpx d2v = csub(Zr, Zkc);
    const cpx wr{-w.x, w.y};
    const cpx wd2 = cmul(wr, d2v);
    const cpx huhr{0.5f * (s2v.x + wd2.y), 0.5f * (s2v.y - wd2.x)};
    const cpx Yk = cmul(gkk, huh);
    const cpx Yrc = cconj(cmul(gkm, huhr));
    const cpx E = cscale(0.5f, cadd(Yk, Yrc));
    const cpx D = cscale(0.5f, csub(Yk, Yrc));
    const cpx O = cmul(cconj(w), D);
    return cpx{E.x - O.y, E.y + O.x};
}

// ---------------------------------------------------------------------------
// Kernel 1: fused tables.
// blocks 0..1024   (h): htab points p = blk*4 + wave (exact fp32 MLP).
// blocks 1025..2049 (g): point pairs {k0,k1,4096-k0,4096-k1}, k0=2b, k1=2b+1;
//   waves 0..3 run the MLP, lane0 stashes gk in LDS; after a barrier threads
//   0..3 emit ab[k] = {A,B}*invn via spectral_eval. gk never hits memory.
// ---------------------------------------------------------------------------
__global__ __launch_bounds__(256) void mlp_tables_kernel(
    const float* __restrict__ kin,
    const float* __restrict__ gw1, const float* __restrict__ gb1,
    const float* __restrict__ gw2, const float* __restrict__ gb2,
    const float* __restrict__ gw3, const float* __restrict__ gb3,
    const float* __restrict__ hw1, const float* __restrict__ hb1,
    const float* __restrict__ hw2, const float* __restrict__ hb2,
    const float* __restrict__ hw3, const float* __restrict__ hb3,
    float4* __restrict__ ab, float* __restrict__ htab) {
    __shared__ __align__(16) float w2s[4096];
    __shared__ float w1s[64], b1s[64], b2s[64], w3as[64], w3bs[64];
    __shared__ cpx gkl[4];
    const int tid = threadIdx.x;
    const bool isH = blockIdx.x < 1025;
    const int b = isH ? blockIdx.x : (blockIdx.x - 1025);
    const float* W2 = isH ? hw2 : gw2;
    for (int i = tid; i < 1024; i += 256)
        ((float4*)w2s)[i] = ((const float4*)W2)[i];
    if (tid < 64) {
        w1s[tid] = isH ? hw1[tid] : gw1[tid];
        b1s[tid] = isH ? hb1[tid] : gb1[tid];
        b2s[tid] = isH ? hb2[tid] : gb2[tid];
        w3as[tid] = isH ? hw3[tid] : gw3[2 * tid];
        w3bs[tid] = isH ? 0.0f : gw3[2 * tid + 1];
    }
    __syncthreads();
    const int wv = tid >> 6, ln = tid & 63;
    // point index for this wave
    int p;
    if (isH) {
        p = b * 4 + wv;
        if (p > 4096) return;          // h-path only; no barrier follows
    } else {
        const int kf = 2 * b + (wv & 1);       // 0..2049
        p = (wv < 2) ? kf : (4096 - kf);       // mirrors for waves 2,3
    }
    const float x = isH ? (-8.0f + (float)p * (16.0f / 4096.0f)) : kin[p];
    float acc = b2s[ln];
#pragma unroll 8
    for (int j = 0; j < 64; ++j) {
        const float h1 = elu(fmaf(x, w1s[j], b1s[j]));
        acc = fmaf(h1, w2s[j * 64 + ln], acc);
    }
    const float e = elu(acc);
    float oa = e * w3as[ln];
    float ob = e * w3bs[ln];
#pragma unroll
    for (int s = 1; s < 64; s <<= 1) {
        oa += __shfl_xor(oa, s, 64);
        ob += __shfl_xor(ob, s, 64);
    }
    if (isH) {
        if (ln == 0) htab[p] = oa + hb3[0];
        return;
    }
    if (ln == 0) gkl[wv] = cpx{oa + gb3[0], ob + gb3[1]};
    __syncthreads();
    // threads 0..3 emit ab entries: pairs (idx, mirror-wave)
    if (tid < 4) {
        const int kf = 2 * b + (tid & 1);
        const int kk = (tid < 2) ? kf : (4096 - kf);
        if (kk <= 4095) {
            const cpx gkk = gkl[tid];
            const cpx gkm = gkl[tid ^ 2];     // its mirror's value
            const float invn = 1.0f / 4096.0f;
            cpx w;
            float ang = -TWO_PI_F * (float)kk / 8192.0f;
            __sincosf(ang, &w.y, &w.x);
            const cpx A = spectral_eval(cpx{1.0f, 0.0f}, cpx{0.0f, 0.0f}, w, gkk, gkm);
            const cpx B = spectral_eval(cpx{0.0f, 0.0f}, cpx{1.0f, 0.0f}, w, gkk, gkm);
            ab[kk] = float4{A.x * invn, A.y * invn, B.x * invn, B.y * invn};
        }
    }
}

// ---------------------------------------------------------------------------
// Kernel 2: one 512-thread block per row, fp16x2 LDS (32KB total).
// Byte-identical to round 22 (validated: ~50us, absmax 0.375).
// ---------------------------------------------------------------------------
__global__ __launch_bounds__(512, 4) void morp_main(
    const float* __restrict__ u, const float* __restrict__ htab,
    const float4* __restrict__ ab, float* __restrict__ out) {
    __shared__ __align__(16) h2 bufA[4096];
    __shared__ __align__(16) h2 bufB[4096];
    const int tid = threadIdx.x;
    const int row = blockIdx.x;

    // ---- precomputed swizzled bases (once per thread)
    const int w3c = (tid >> 6) & 7;                           // wave id
    const int s0 = swz(tid);                                  // +512t
    const int b1 = (tid & 63) + 512 * (tid >> 6);
    const int s1 = b1 ^ ((b1 >> 3) & 7);                      // ^68t
    const int b2 = (tid & 7) + 64 * (tid >> 3);
    const int s2 = b2 ^ (((tid >> 3) & 7) << 2);              // ^9t
    const int b3 = 8 * (tid & 7) + 64 * (tid >> 3);
    const int s3r = b3 ^ (tid & 7) ^ (((tid >> 3) & 7) << 2); // ^t
    const int m3 = (tid >> 6) + 8 * ((tid >> 3) & 7) + 64 * (tid & 7);
    const int s3w = swz(m3);                                  // +512t
    const int bq = 8 * (m3 & 7) + 64 * (m3 >> 3);
    const int s3g = bq ^ (m3 & 7) ^ (((m3 >> 3) & 7) << 2) ^ ((m3 >> 6) & 7);
    const int sm = swz(4096 - tid);                           // mirror: -512c
    const int k4 = tid >> 6;
    const int m2 = (tid >> 6) + 8 * ((tid >> 3) & 7);

    // ---- fused table-lerp + forward stage 0 (DFT8 over t4) -> bufA
    {
        const float2* urow2 = (const float2*)(u + (size_t)row * 8192);
        cpx v[8];
#pragma unroll
        for (int t = 0; t < 8; ++t) {
            const float2 uv = urow2[tid + 512 * t];
            float t0 = fmaf(uv.x, 256.0f, 2048.0f);
            t0 = fminf(fmaxf(t0, 0.0f), 4095.0f);
            const float fi0 = floorf(t0);
            const int i0 = (int)fi0;
            const float h00 = htab[i0], h01 = htab[i0 + 1];
            float t1 = fmaf(uv.y, 256.0f, 2048.0f);
            t1 = fminf(fmaxf(t1, 0.0f), 4095.0f);
            const float fi1 = floorf(t1);
            const int i1 = (int)fi1;
            const float h10 = htab[i1], h11 = htab[i1 + 1];
            v[t] = cpx{fmaf(t0 - fi0, h01 - h00, h00),
                       fmaf(t1 - fi1, h11 - h10, h10)};
        }
        dft8<-1>(v);
        h2* __restrict__ p = bufA + s0;
#pragma unroll
        for (int t = 0; t < 8; ++t) p[512 * t] = cpk(v[t]);
    }
    __syncthreads();                       // cross-wave (S0 scatter)
    stage1<-1>(bufA, bufB, s1, k4);
    asm volatile("" ::: "memory");         // wave-confined handoff (safe)
    stage2<-1>(bufB, bufA, s2, s2, m2);
    __syncthreads();                       // protects S3's cross-block WRITE
    stage3<-1>(bufA, bufB, s3r, s3w, m3);
    __syncthreads();                       // cross-wave (S3 scatter + mirror)

    // ---- fused spectral (bilinear A/B) + inverse stage 0: B -> A
    {
        cpx zres[8];
        const h2* __restrict__ pk = bufB + s0;
        const int c0mir = (tid == 0) ? 0 : sm;
#pragma unroll
        for (int c = 0; c < 8; ++c) {
            const int k = tid + 512 * c;
            const float4 abv = ab[k];
            const cpx Zk = cup(pk[512 * c]);
            const cpx Zc = cconj(cup(bufB[c == 0 ? c0mir : (sm - 512 * c)]));
            const cpx az = cmul(cpx{abv.x, abv.y}, Zk);
            const cpx bz = cmul(cpx{abv.z, abv.w}, Zc);
            zres[c] = cadd(az, bz);
        }
        dft8<1>(zres);
        h2* __restrict__ pw = bufA + s0;
#pragma unroll
        for (int c = 0; c < 8; ++c) pw[512 * c] = cpk(zres[c]);
    }
    __syncthreads();                       // cross-wave (invS0 scatter)
    stage1<1>(bufA, bufB, s1, k4);
    asm volatile("" ::: "memory");         // wave-confined handoff (safe)
    stage2<1>(bufB, bufA, s2, s2 ^ w3c, m2);   // write generation in swz3
    __syncthreads();                       // cross-wave (relabeled S3g read)

    // ---- inverse S3, relabeled q = m3: read bufA (swz3), twiddle index tid,
    // write GLOBAL coalesced at n = tid + 512t. No copy-out.
    {
        cpx v[8];
#pragma unroll
        for (int t = 0; t < 8; ++t) v[t] = cup(bufA[s3g ^ t]);
        twiddle8<1>(v, (TWO_PI_F / 4096.0f) * (float)tid);
        dft8<1>(v);
        cpx* orow = (cpx*)(out + (size_t)row * 8192);
#pragma unroll
        for (int t = 0; t < 8; ++t) orow[tid + 512 * t] = v[t];
    }
}

extern "C" void kernel_launch(void* const* d_in, const int* in_sizes, int n_in,
                              void* d_out, int out_size, void* d_ws, size_t ws_size,
                              hipStream_t stream) {
    const float* u   = (const float*)d_in[0];
    const float* kin = (const float*)d_in[1];
    const float* hw1 = (const float*)d_in[2];
    const float* hb1 = (const float*)d_in[3];
    const float* hw2 = (const float*)d_in[4];
    const float* hb2 = (const float*)d_in[5];
    const float* hw3 = (const float*)d_in[6];
    const float* hb3 = (const float*)d_in[7];
    const float* gw1 = (const float*)d_in[8];
    const float* gb1 = (const float*)d_in[9];
    const float* gw2 = (const float*)d_in[10];
    const float* gb2 = (const float*)d_in[11];
    const float* gw3 = (const float*)d_in[12];
    const float* gb3 = (const float*)d_in[13];

    float* htab = (float*)d_ws;                         // 4097*4 = 16388 B
    float4* ab = (float4*)((char*)d_ws + 16512);        // 4096*16 = 65536 B
    mlp_tables_kernel<<<2050, 256, 0, stream>>>(
        kin, gw1, gb1, gw2, gb2, gw3, gb3,
        hw1, hb1, hw2, hb2, hw3, hb3, ab, htab);
    morp_main<<<2048, 512, 0, stream>>>(u, htab, ab, (float*)d_out);
}